// Round 1
// baseline (16921.378 us; speedup 1.0000x reference)
//
#include <hip/hip_runtime.h>
#include <math.h>

#define THREADS 256

// ---------------- degree / dis ----------------
__global__ void deg_kernel(const int* __restrict__ row, float* __restrict__ deg, int E) {
    int e = blockIdx.x * blockDim.x + threadIdx.x;
    if (e < E) atomicAdd(&deg[row[e]], 1.0f);
}

__global__ void dis_kernel(float* __restrict__ deg, int N) {
    int i = blockIdx.x * blockDim.x + threadIdx.x;
    if (i < N) {
        float d = deg[i];
        deg[i] = d > 0.f ? rsqrtf(fmaxf(d, 1.f)) : 0.f;
    }
}

// ---------------- edge aggregation: acc[col] += w * feat[row] ----------------
template<int FD>
__global__ void agg_kernel(const int* __restrict__ row, const int* __restrict__ col,
                           const float* __restrict__ dis, const float* __restrict__ feat,
                           float* __restrict__ acc, int E) {
    int e = blockIdx.x * blockDim.x + threadIdx.x;
    if (e >= E) return;
    int r = row[e], c = col[e];
    float w = -(dis[r] * dis[c]);
    const float4* fr = reinterpret_cast<const float4*>(feat + (size_t)r * FD);
    float* ac = acc + (size_t)c * FD;
#pragma unroll
    for (int v = 0; v < FD / 4; ++v) {
        float4 q = fr[v];
        atomicAdd(&ac[v * 4 + 0], w * q.x);
        atomicAdd(&ac[v * 4 + 1], w * q.y);
        atomicAdd(&ac[v * 4 + 2], w * q.z);
        atomicAdd(&ac[v * 4 + 3], w * q.w);
    }
}

// ---------------- dense layer 1: h = relu(x@W0 + tx@W1 + b) ----------------
template<int IN, int OUT>
__global__ void dense_relu_kernel(const float* __restrict__ feat, const float* __restrict__ agg,
                                  const float* __restrict__ W0, const float* __restrict__ W1,
                                  const float* __restrict__ b, float* __restrict__ out, int n) {
    __shared__ float sW0[IN * OUT], sW1[IN * OUT], sb[OUT];
    for (int i = threadIdx.x; i < IN * OUT; i += blockDim.x) { sW0[i] = W0[i]; sW1[i] = W1[i]; }
    if (threadIdx.x < OUT) sb[threadIdx.x] = b[threadIdx.x];
    __syncthreads();
    int node = blockIdx.x * blockDim.x + threadIdx.x;
    if (node >= n) return;
    float acc[OUT];
#pragma unroll
    for (int c = 0; c < OUT; ++c) acc[c] = sb[c];
#pragma unroll
    for (int f = 0; f < IN; ++f) {
        float a = feat[(size_t)node * IN + f];
        float g = agg[(size_t)node * IN + f];
#pragma unroll
        for (int c = 0; c < OUT; ++c) acc[c] += a * sW0[f * OUT + c] + g * sW1[f * OUT + c];
    }
#pragma unroll
    for (int c = 0; c < OUT; ++c) out[(size_t)node * OUT + c] = fmaxf(acc[c], 0.f);
}

// ---------------- dense layer 2 + readout: s = relu(h@W0 + tx@W1 + b) @ Wr + br ----------------
__global__ void dense2_readout_kernel(const float* __restrict__ feat, const float* __restrict__ agg,
                                      const float* __restrict__ W0, const float* __restrict__ W1,
                                      const float* __restrict__ b, const float* __restrict__ Wr,
                                      const float* __restrict__ br, float* __restrict__ s, int n) {
    constexpr int IN = 16, OUT = 16;
    __shared__ float sW0[IN * OUT], sW1[IN * OUT], sb[OUT], sWr[OUT], sbr;
    for (int i = threadIdx.x; i < IN * OUT; i += blockDim.x) { sW0[i] = W0[i]; sW1[i] = W1[i]; }
    if (threadIdx.x < OUT) { sb[threadIdx.x] = b[threadIdx.x]; sWr[threadIdx.x] = Wr[threadIdx.x]; }
    if (threadIdx.x == 0) sbr = br[0];
    __syncthreads();
    int node = blockIdx.x * blockDim.x + threadIdx.x;
    if (node >= n) return;
    float acc[OUT];
#pragma unroll
    for (int c = 0; c < OUT; ++c) acc[c] = sb[c];
#pragma unroll
    for (int f = 0; f < IN; ++f) {
        float a = feat[(size_t)node * IN + f];
        float g = agg[(size_t)node * IN + f];
#pragma unroll
        for (int c = 0; c < OUT; ++c) acc[c] += a * sW0[f * OUT + c] + g * sW1[f * OUT + c];
    }
    float sv = sbr;
#pragma unroll
    for (int c = 0; c < OUT; ++c) sv += fmaxf(acc[c], 0.f) * sWr[c];
    s[node] = sv;
}

// ---------------- segment softmax ----------------
__global__ void init_m_kernel(float* __restrict__ m, int G) {
    int i = blockIdx.x * blockDim.x + threadIdx.x;
    if (i < G) m[i] = -INFINITY;
}

__device__ inline void atomicMaxF(float* addr, float val) {
    if (val >= 0.f) atomicMax((int*)addr, __float_as_int(val));
    else            atomicMin((unsigned int*)addr, __float_as_uint(val));
}

__global__ void smax_kernel(const float* __restrict__ s, const int* __restrict__ batch,
                            float* __restrict__ m, int N) {
    int i = blockIdx.x * blockDim.x + threadIdx.x;
    if (i < N) atomicMaxF(&m[batch[i]], s[i]);
}

__global__ void sexp_kernel(const float* __restrict__ s, const int* __restrict__ batch,
                            const float* __restrict__ m, float* __restrict__ z,
                            float* __restrict__ out, int N) {
    int i = blockIdx.x * blockDim.x + threadIdx.x;
    if (i < N) {
        int b = batch[i];
        float e = expf(s[i] - m[b]);
        out[i] = e;
        atomicAdd(&z[b], e);
    }
}

__global__ void sdiv_kernel(const int* __restrict__ batch, const float* __restrict__ z,
                            float* __restrict__ out, int N) {
    int i = blockIdx.x * blockDim.x + threadIdx.x;
    if (i < N) out[i] /= z[batch[i]];
}

extern "C" void kernel_launch(void* const* d_in, const int* in_sizes, int n_in,
                              void* d_out, int out_size, void* d_ws, size_t ws_size,
                              hipStream_t stream) {
    const float* x     = (const float*)d_in[0];
    const int*   ei    = (const int*)d_in[1];
    const int*   batch = (const int*)d_in[2];
    const float* W1_0  = (const float*)d_in[3];
    const float* W1_1  = (const float*)d_in[4];
    const float* b1    = (const float*)d_in[5];
    const float* W2_0  = (const float*)d_in[6];
    const float* W2_1  = (const float*)d_in[7];
    const float* b2    = (const float*)d_in[8];
    const float* Wr    = (const float*)d_in[9];
    const float* br    = (const float*)d_in[10];
    float* out = (float*)d_out;

    const int N = in_sizes[2];
    const int E = in_sizes[1] / 2;
    const int G = 256;
    const int* row = ei;
    const int* col = ei + E;

    float* ws = (float*)d_ws;
    float* deg = ws;                          // N  (becomes dis in place)
    float* tx1 = deg + N;                     // 8N
    float* tx2 = tx1 + (size_t)8 * N;         // 16N
    float* z   = tx2 + (size_t)16 * N;        // G
    float* h1  = z + G;                       // 16N
    float* s   = h1 + (size_t)16 * N;         // N
    float* m   = s + N;                       // G

    // zero deg + tx1 + tx2 + z in one contiguous memset
    hipMemsetAsync(deg, 0, sizeof(float) * ((size_t)25 * N + G), stream);

    int gE = (E + THREADS - 1) / THREADS;
    int gN = (N + THREADS - 1) / THREADS;

    deg_kernel<<<gE, THREADS, 0, stream>>>(row, deg, E);
    dis_kernel<<<gN, THREADS, 0, stream>>>(deg, N);
    agg_kernel<8><<<gE, THREADS, 0, stream>>>(row, col, deg, x, tx1, E);
    dense_relu_kernel<8, 16><<<gN, THREADS, 0, stream>>>(x, tx1, W1_0, W1_1, b1, h1, N);
    agg_kernel<16><<<gE, THREADS, 0, stream>>>(row, col, deg, h1, tx2, E);
    dense2_readout_kernel<<<gN, THREADS, 0, stream>>>(h1, tx2, W2_0, W2_1, b2, Wr, br, s, N);
    init_m_kernel<<<1, G, 0, stream>>>(m, G);
    smax_kernel<<<gN, THREADS, 0, stream>>>(s, batch, m, N);
    sexp_kernel<<<gN, THREADS, 0, stream>>>(s, batch, m, z, out, N);
    sdiv_kernel<<<gN, THREADS, 0, stream>>>(batch, z, out, N);
}

// Round 2
// 2623.307 us; speedup vs baseline: 6.4504x; 6.4504x over previous
//
#include <hip/hip_runtime.h>
#include <math.h>

#define THREADS 256

// ======================= fast path: CSR build + gather =======================

__global__ void deg_cnt_kernel(const int* __restrict__ row, const int* __restrict__ col,
                               int* __restrict__ deg_i, int* __restrict__ cnt, int E) {
    int e = blockIdx.x * blockDim.x + threadIdx.x;
    if (e >= E) return;
    atomicAdd(&deg_i[row[e]], 1);
    atomicAdd(&cnt[col[e]], 1);
}

__global__ void dis_kernel_i(const int* __restrict__ deg_i, float* __restrict__ dis, int N) {
    int i = blockIdx.x * blockDim.x + threadIdx.x;
    if (i < N) {
        int d = deg_i[i];
        dis[i] = d > 0 ? rsqrtf((float)d) : 0.f;
    }
}

// block-wise exclusive scan
__global__ void scan1_kernel(const int* __restrict__ cnt, int* __restrict__ off,
                             int* __restrict__ bsum, int n) {
    __shared__ int tmp[THREADS];
    int i = blockIdx.x * THREADS + threadIdx.x;
    int v = (i < n) ? cnt[i] : 0;
    tmp[threadIdx.x] = v;
    __syncthreads();
    for (int d = 1; d < THREADS; d <<= 1) {
        int t = (threadIdx.x >= d) ? tmp[threadIdx.x - d] : 0;
        __syncthreads();
        tmp[threadIdx.x] += t;
        __syncthreads();
    }
    if (i < n) off[i] = tmp[threadIdx.x] - v;
    if (threadIdx.x == THREADS - 1) bsum[blockIdx.x] = tmp[threadIdx.x];
}

__global__ void scan2_kernel(int* __restrict__ bsum, int nb) {
    __shared__ int tmp[1024];
    int carry = 0;
    for (int base = 0; base < nb; base += 1024) {
        int i = base + threadIdx.x;
        int v = (i < nb) ? bsum[i] : 0;
        tmp[threadIdx.x] = v;
        __syncthreads();
        for (int d = 1; d < 1024; d <<= 1) {
            int t = (threadIdx.x >= d) ? tmp[threadIdx.x - d] : 0;
            __syncthreads();
            tmp[threadIdx.x] += t;
            __syncthreads();
        }
        if (i < nb) bsum[i] = carry + tmp[threadIdx.x] - v;
        int total = tmp[1023];
        __syncthreads();
        carry += total;
    }
}

__global__ void scan3_kernel(int* __restrict__ off, const int* __restrict__ bsum, int n) {
    int i = blockIdx.x * THREADS + threadIdx.x;
    if (i < n) off[i] += bsum[blockIdx.x];
}

__global__ void fill_csr_kernel(const int* __restrict__ row, const int* __restrict__ col,
                                const int* __restrict__ off, int* __restrict__ fill,
                                int* __restrict__ csr_src, int E) {
    int e = blockIdx.x * blockDim.x + threadIdx.x;
    if (e >= E) return;
    int c = col[e];
    int p = off[c] + atomicAdd(&fill[c], 1);
    csr_src[p] = row[e];
}

// gather tx1 (F=8) + dense layer1 (8->16) + relu, fused
__global__ void gather_dense1_kernel(const int* __restrict__ off, const int* __restrict__ csr_src,
                                     const float* __restrict__ dis, const float* __restrict__ x,
                                     const float* __restrict__ W0, const float* __restrict__ W1,
                                     const float* __restrict__ b, float* __restrict__ h1,
                                     int N, int E) {
    __shared__ float sW0[8 * 16], sW1[8 * 16], sb[16];
    for (int i = threadIdx.x; i < 128; i += blockDim.x) { sW0[i] = W0[i]; sW1[i] = W1[i]; }
    if (threadIdx.x < 16) sb[threadIdx.x] = b[threadIdx.x];
    __syncthreads();
    int c = blockIdx.x * blockDim.x + threadIdx.x;
    if (c >= N) return;
    int p0 = off[c], p1 = (c == N - 1) ? E : off[c + 1];
    float tx[8] = {0, 0, 0, 0, 0, 0, 0, 0};
    for (int p = p0; p < p1; ++p) {
        int src = csr_src[p];
        float wv = dis[src];
        const float4* fr = reinterpret_cast<const float4*>(x + (size_t)src * 8);
        float4 a = fr[0], bb = fr[1];
        tx[0] += wv * a.x;  tx[1] += wv * a.y;  tx[2] += wv * a.z;  tx[3] += wv * a.w;
        tx[4] += wv * bb.x; tx[5] += wv * bb.y; tx[6] += wv * bb.z; tx[7] += wv * bb.w;
    }
    float sc = -dis[c];
    float xa[8];
    const float4* xr = reinterpret_cast<const float4*>(x + (size_t)c * 8);
    float4 a = xr[0], bb = xr[1];
    xa[0] = a.x; xa[1] = a.y; xa[2] = a.z; xa[3] = a.w;
    xa[4] = bb.x; xa[5] = bb.y; xa[6] = bb.z; xa[7] = bb.w;
    float acc[16];
#pragma unroll
    for (int o = 0; o < 16; ++o) acc[o] = sb[o];
#pragma unroll
    for (int f = 0; f < 8; ++f) {
        float xv = xa[f], tv = sc * tx[f];
#pragma unroll
        for (int o = 0; o < 16; ++o) acc[o] += xv * sW0[f * 16 + o] + tv * sW1[f * 16 + o];
    }
    float4* outp = reinterpret_cast<float4*>(h1 + (size_t)c * 16);
#pragma unroll
    for (int v = 0; v < 4; ++v) {
        float4 q;
        q.x = fmaxf(acc[v * 4 + 0], 0.f);
        q.y = fmaxf(acc[v * 4 + 1], 0.f);
        q.z = fmaxf(acc[v * 4 + 2], 0.f);
        q.w = fmaxf(acc[v * 4 + 3], 0.f);
        outp[v] = q;
    }
}

// gather tx2 (C=16) + dense layer2 (16->16) + relu + readout, fused
__global__ void gather_dense2_kernel(const int* __restrict__ off, const int* __restrict__ csr_src,
                                     const float* __restrict__ dis, const float* __restrict__ h1,
                                     const float* __restrict__ W0, const float* __restrict__ W1,
                                     const float* __restrict__ b, const float* __restrict__ Wr,
                                     const float* __restrict__ br, float* __restrict__ s,
                                     int N, int E) {
    __shared__ float sW0[16 * 16], sW1[16 * 16], sb[16], sWr[16], sbr;
    for (int i = threadIdx.x; i < 256; i += blockDim.x) { sW0[i] = W0[i]; sW1[i] = W1[i]; }
    if (threadIdx.x < 16) { sb[threadIdx.x] = b[threadIdx.x]; sWr[threadIdx.x] = Wr[threadIdx.x]; }
    if (threadIdx.x == 0) sbr = br[0];
    __syncthreads();
    int c = blockIdx.x * blockDim.x + threadIdx.x;
    if (c >= N) return;
    int p0 = off[c], p1 = (c == N - 1) ? E : off[c + 1];
    float tx[16];
#pragma unroll
    for (int o = 0; o < 16; ++o) tx[o] = 0.f;
    for (int p = p0; p < p1; ++p) {
        int src = csr_src[p];
        float wv = dis[src];
        const float4* fr = reinterpret_cast<const float4*>(h1 + (size_t)src * 16);
#pragma unroll
        for (int v = 0; v < 4; ++v) {
            float4 q = fr[v];
            tx[v * 4 + 0] += wv * q.x;
            tx[v * 4 + 1] += wv * q.y;
            tx[v * 4 + 2] += wv * q.z;
            tx[v * 4 + 3] += wv * q.w;
        }
    }
    float sc = -dis[c];
    float ha[16];
    const float4* hr = reinterpret_cast<const float4*>(h1 + (size_t)c * 16);
#pragma unroll
    for (int v = 0; v < 4; ++v) {
        float4 q = hr[v];
        ha[v * 4 + 0] = q.x; ha[v * 4 + 1] = q.y; ha[v * 4 + 2] = q.z; ha[v * 4 + 3] = q.w;
    }
    float acc[16];
#pragma unroll
    for (int o = 0; o < 16; ++o) acc[o] = sb[o];
#pragma unroll
    for (int f = 0; f < 16; ++f) {
        float hv = ha[f], tv = sc * tx[f];
#pragma unroll
        for (int o = 0; o < 16; ++o) acc[o] += hv * sW0[f * 16 + o] + tv * sW1[f * 16 + o];
    }
    float sv = sbr;
#pragma unroll
    for (int o = 0; o < 16; ++o) sv += fmaxf(acc[o], 0.f) * sWr[o];
    s[c] = sv;
}

// block-per-graph segment softmax (batch is sorted)
__global__ void softmax_kernel(const float* __restrict__ s, const int* __restrict__ batch,
                               float* __restrict__ out, int N) {
    int g = blockIdx.x;
    __shared__ float red[THREADS];
    int lo, hi;
    { int a = 0, b = N; while (a < b) { int mid = (a + b) >> 1; if (batch[mid] < g) a = mid + 1; else b = mid; } lo = a; }
    { int a = lo, b = N; while (a < b) { int mid = (a + b) >> 1; if (batch[mid] < g + 1) a = mid + 1; else b = mid; } hi = a; }
    float mx = -INFINITY;
    for (int i = lo + threadIdx.x; i < hi; i += THREADS) mx = fmaxf(mx, s[i]);
    red[threadIdx.x] = mx;
    __syncthreads();
    for (int d = THREADS / 2; d > 0; d >>= 1) {
        if (threadIdx.x < d) red[threadIdx.x] = fmaxf(red[threadIdx.x], red[threadIdx.x + d]);
        __syncthreads();
    }
    mx = red[0];
    __syncthreads();
    float sum = 0.f;
    for (int i = lo + threadIdx.x; i < hi; i += THREADS) sum += expf(s[i] - mx);
    red[threadIdx.x] = sum;
    __syncthreads();
    for (int d = THREADS / 2; d > 0; d >>= 1) {
        if (threadIdx.x < d) red[threadIdx.x] += red[threadIdx.x + d];
        __syncthreads();
    }
    float inv = 1.f / red[0];
    for (int i = lo + threadIdx.x; i < hi; i += THREADS) out[i] = expf(s[i] - mx) * inv;
}

// ======================= fallback path (round-1, atomic scatter) =======================

__global__ void deg_kernel(const int* __restrict__ row, float* __restrict__ deg, int E) {
    int e = blockIdx.x * blockDim.x + threadIdx.x;
    if (e < E) atomicAdd(&deg[row[e]], 1.0f);
}

__global__ void dis_kernel(float* __restrict__ deg, int N) {
    int i = blockIdx.x * blockDim.x + threadIdx.x;
    if (i < N) {
        float d = deg[i];
        deg[i] = d > 0.f ? rsqrtf(fmaxf(d, 1.f)) : 0.f;
    }
}

template<int FD>
__global__ void agg_kernel(const int* __restrict__ row, const int* __restrict__ col,
                           const float* __restrict__ dis, const float* __restrict__ feat,
                           float* __restrict__ acc, int E) {
    int e = blockIdx.x * blockDim.x + threadIdx.x;
    if (e >= E) return;
    int r = row[e], c = col[e];
    float w = -(dis[r] * dis[c]);
    const float4* fr = reinterpret_cast<const float4*>(feat + (size_t)r * FD);
    float* ac = acc + (size_t)c * FD;
#pragma unroll
    for (int v = 0; v < FD / 4; ++v) {
        float4 q = fr[v];
        atomicAdd(&ac[v * 4 + 0], w * q.x);
        atomicAdd(&ac[v * 4 + 1], w * q.y);
        atomicAdd(&ac[v * 4 + 2], w * q.z);
        atomicAdd(&ac[v * 4 + 3], w * q.w);
    }
}

template<int IN, int OUT>
__global__ void dense_relu_kernel(const float* __restrict__ feat, const float* __restrict__ agg,
                                  const float* __restrict__ W0, const float* __restrict__ W1,
                                  const float* __restrict__ b, float* __restrict__ out, int n) {
    __shared__ float sW0[IN * OUT], sW1[IN * OUT], sb[OUT];
    for (int i = threadIdx.x; i < IN * OUT; i += blockDim.x) { sW0[i] = W0[i]; sW1[i] = W1[i]; }
    if (threadIdx.x < OUT) sb[threadIdx.x] = b[threadIdx.x];
    __syncthreads();
    int node = blockIdx.x * blockDim.x + threadIdx.x;
    if (node >= n) return;
    float acc[OUT];
#pragma unroll
    for (int c = 0; c < OUT; ++c) acc[c] = sb[c];
#pragma unroll
    for (int f = 0; f < IN; ++f) {
        float a = feat[(size_t)node * IN + f];
        float g = agg[(size_t)node * IN + f];
#pragma unroll
        for (int c = 0; c < OUT; ++c) acc[c] += a * sW0[f * OUT + c] + g * sW1[f * OUT + c];
    }
#pragma unroll
    for (int c = 0; c < OUT; ++c) out[(size_t)node * OUT + c] = fmaxf(acc[c], 0.f);
}

__global__ void dense2_readout_kernel(const float* __restrict__ feat, const float* __restrict__ agg,
                                      const float* __restrict__ W0, const float* __restrict__ W1,
                                      const float* __restrict__ b, const float* __restrict__ Wr,
                                      const float* __restrict__ br, float* __restrict__ s, int n) {
    constexpr int IN = 16, OUT = 16;
    __shared__ float sW0[IN * OUT], sW1[IN * OUT], sb[OUT], sWr[OUT], sbr;
    for (int i = threadIdx.x; i < IN * OUT; i += blockDim.x) { sW0[i] = W0[i]; sW1[i] = W1[i]; }
    if (threadIdx.x < OUT) { sb[threadIdx.x] = b[threadIdx.x]; sWr[threadIdx.x] = Wr[threadIdx.x]; }
    if (threadIdx.x == 0) sbr = br[0];
    __syncthreads();
    int node = blockIdx.x * blockDim.x + threadIdx.x;
    if (node >= n) return;
    float acc[OUT];
#pragma unroll
    for (int c = 0; c < OUT; ++c) acc[c] = sb[c];
#pragma unroll
    for (int f = 0; f < IN; ++f) {
        float a = feat[(size_t)node * IN + f];
        float g = agg[(size_t)node * IN + f];
#pragma unroll
        for (int c = 0; c < OUT; ++c) acc[c] += a * sW0[f * OUT + c] + g * sW1[f * OUT + c];
    }
    float sv = sbr;
#pragma unroll
    for (int c = 0; c < OUT; ++c) sv += fmaxf(acc[c], 0.f) * sWr[c];
    s[node] = sv;
}

__global__ void init_m_kernel(float* __restrict__ m, int G) {
    int i = blockIdx.x * blockDim.x + threadIdx.x;
    if (i < G) m[i] = -INFINITY;
}

__device__ inline void atomicMaxF(float* addr, float val) {
    if (val >= 0.f) atomicMax((int*)addr, __float_as_int(val));
    else            atomicMin((unsigned int*)addr, __float_as_uint(val));
}

__global__ void smax_kernel(const float* __restrict__ s, const int* __restrict__ batch,
                            float* __restrict__ m, int N) {
    int i = blockIdx.x * blockDim.x + threadIdx.x;
    if (i < N) atomicMaxF(&m[batch[i]], s[i]);
}

__global__ void sexp_kernel(const float* __restrict__ s, const int* __restrict__ batch,
                            const float* __restrict__ m, float* __restrict__ z,
                            float* __restrict__ out, int N) {
    int i = blockIdx.x * blockDim.x + threadIdx.x;
    if (i < N) {
        int b = batch[i];
        float e = expf(s[i] - m[b]);
        out[i] = e;
        atomicAdd(&z[b], e);
    }
}

__global__ void sdiv_kernel(const int* __restrict__ batch, const float* __restrict__ z,
                            float* __restrict__ out, int N) {
    int i = blockIdx.x * blockDim.x + threadIdx.x;
    if (i < N) out[i] /= z[batch[i]];
}

// ======================= launch =======================

extern "C" void kernel_launch(void* const* d_in, const int* in_sizes, int n_in,
                              void* d_out, int out_size, void* d_ws, size_t ws_size,
                              hipStream_t stream) {
    const float* x     = (const float*)d_in[0];
    const int*   ei    = (const int*)d_in[1];
    const int*   batch = (const int*)d_in[2];
    const float* W1_0  = (const float*)d_in[3];
    const float* W1_1  = (const float*)d_in[4];
    const float* b1    = (const float*)d_in[5];
    const float* W2_0  = (const float*)d_in[6];
    const float* W2_1  = (const float*)d_in[7];
    const float* b2    = (const float*)d_in[8];
    const float* Wr    = (const float*)d_in[9];
    const float* br    = (const float*)d_in[10];
    float* out = (float*)d_out;

    const int N = in_sizes[2];
    const int E = in_sizes[1] / 2;
    const int G = 256;
    const int* row = ei;
    const int* col = ei + E;

    const int gE = (E + THREADS - 1) / THREADS;
    const int gN = (N + THREADS - 1) / THREADS;
    const int nb = gN;  // scan blocks over N

    // fast-path workspace layout (elements)
    //  deg_i N | cnt N | fill N | off N | bsum 1024 | dis N | h1 16N | s N | csr E
    size_t need = sizeof(int) * ((size_t)4 * N + 1024) +
                  sizeof(float) * ((size_t)18 * N) +
                  sizeof(int) * (size_t)E;

    if (ws_size >= need) {
        int* deg_i = (int*)d_ws;
        int* cnt   = deg_i + N;
        int* fill  = cnt + N;
        int* off   = fill + N;
        int* bsum  = off + N;
        float* dis = (float*)(bsum + 1024);
        float* h1  = dis + N;
        float* s   = h1 + (size_t)16 * N;
        int* csr   = (int*)(s + N);

        hipMemsetAsync(deg_i, 0, sizeof(int) * (size_t)3 * N, stream);  // deg_i, cnt, fill

        deg_cnt_kernel<<<gE, THREADS, 0, stream>>>(row, col, deg_i, cnt, E);
        dis_kernel_i<<<gN, THREADS, 0, stream>>>(deg_i, dis, N);
        scan1_kernel<<<nb, THREADS, 0, stream>>>(cnt, off, bsum, N);
        scan2_kernel<<<1, 1024, 0, stream>>>(bsum, nb);
        scan3_kernel<<<nb, THREADS, 0, stream>>>(off, bsum, N);
        fill_csr_kernel<<<gE, THREADS, 0, stream>>>(row, col, off, fill, csr, E);
        gather_dense1_kernel<<<gN, THREADS, 0, stream>>>(off, csr, dis, x, W1_0, W1_1, b1, h1, N, E);
        gather_dense2_kernel<<<gN, THREADS, 0, stream>>>(off, csr, dis, h1, W2_0, W2_1, b2, Wr, br, s, N, E);
        softmax_kernel<<<G, THREADS, 0, stream>>>(s, batch, out, N);
    } else {
        // fallback: round-1 atomic path
        float* ws = (float*)d_ws;
        float* deg = ws;
        float* tx1 = deg + N;
        float* tx2 = tx1 + (size_t)8 * N;
        float* z   = tx2 + (size_t)16 * N;
        float* h1  = z + G;
        float* s   = h1 + (size_t)16 * N;
        float* m   = s + N;

        hipMemsetAsync(deg, 0, sizeof(float) * ((size_t)25 * N + G), stream);

        deg_kernel<<<gE, THREADS, 0, stream>>>(row, deg, E);
        dis_kernel<<<gN, THREADS, 0, stream>>>(deg, N);
        agg_kernel<8><<<gE, THREADS, 0, stream>>>(row, col, deg, x, tx1, E);
        dense_relu_kernel<8, 16><<<gN, THREADS, 0, stream>>>(x, tx1, W1_0, W1_1, b1, h1, N);
        agg_kernel<16><<<gE, THREADS, 0, stream>>>(row, col, deg, h1, tx2, E);
        dense2_readout_kernel<<<gN, THREADS, 0, stream>>>(h1, tx2, W2_0, W2_1, b2, Wr, br, s, N);
        init_m_kernel<<<1, G, 0, stream>>>(m, G);
        smax_kernel<<<gN, THREADS, 0, stream>>>(s, batch, m, N);
        sexp_kernel<<<gN, THREADS, 0, stream>>>(s, batch, m, z, out, N);
        sdiv_kernel<<<gN, THREADS, 0, stream>>>(batch, z, out, N);
    }
}